// Round 6
// baseline (3691.077 us; speedup 1.0000x reference)
//
#include <hip/hip_runtime.h>
#include <cstdint>

// ---------------------------------------------------------------------------
// QLoRABigNet. Split-bf16 (hi+lo, 3-product) GEMM expressed as ONE K-concat
// bf16 GEMM: KC = 3*1088, X-chunks [xh|xh|xl] (source map), W = [wh|wl|wh].
// GEMM: faithful m201 8-phase template: 256x256 tile, BK=64, 512 thr/8 waves,
// 128 KiB dbuf LDS, per-phase {ds_read || stage half-tile -> barrier ->
// lgkmcnt(0) -> setprio(1) 16 MFMA setprio(0) -> barrier}, counted vmcnt(4)
// once per K-tile (derived: B(t+2) halves in flight = 2 loads x 2), XCD
// row-panel grouping (R5-proven: FETCH 135->70 MB).
// t_k / ln_k / pack_x / pack_a unchanged from R5 (verified).
// ---------------------------------------------------------------------------

#define NTOK 16384
#define DIM  1024
#define KP   1088                 // one chunk (1024 + 32 lora + 32 pad)
#define KC   3264                 // W storage: [wh | wl | wh]
#define NSTEP 51                  // KC / 64
#define RLORA 32
#define NLIN 18
#define NBLK 6

typedef unsigned short u16;
typedef __attribute__((ext_vector_type(8))) short short8;
typedef __attribute__((ext_vector_type(4))) float f32x4;

__device__ __forceinline__ u16 f2bf(float f) {
  uint32_t u = __float_as_uint(f);
  u += 0x7fffu + ((u >> 16) & 1u);          // round-to-nearest-even
  return (u16)(u >> 16);
}
__device__ __forceinline__ float bf2f(u16 h) {
  return __uint_as_float(((uint32_t)h) << 16);
}
__device__ __forceinline__ void split_bf(float f, u16& h, u16& l) {
  h = f2bf(f);
  l = f2bf(f - bf2f(h));                    // exact residual
}
__device__ __forceinline__ void gld16(const void* g, void* lds) {
  __builtin_amdgcn_global_load_lds(
      (const __attribute__((address_space(1))) uint32_t*)g,
      (__attribute__((address_space(3))) uint32_t*)lds, 16, 0, 0);
}

// ---------------------------------------------------------------------------
// pack_w: one layer -> Wcat rows of KC=3264:
// [wh(1024)|Bh(32)|0(32) | wl(1024)|Bl(32)|0(32) | wh(1024)|Bh(32)|0(32)]
// (verified in R3)
// ---------------------------------------------------------------------------
__global__ void pack_w_k(const int* __restrict__ qw, const float* __restrict__ sc,
                         const float* __restrict__ lb, u16* __restrict__ Wc) {
  const int idx = blockIdx.x * 256 + threadIdx.x;
  if (idx >= 1024 * (KC / 16)) return;
  const int c = idx % (KC / 16);
  const int o = idx / (KC / 16);
  int kind = 4, g = 0;  // 0: w-hi, 1: w-lo, 2: B-hi, 3: B-lo, 4: zero
  if      (c < 64)  { kind = 0; g = c; }
  else if (c < 66)  { kind = 2; g = c - 64; }
  else if (c < 68)  { kind = 4; }
  else if (c < 132) { kind = 1; g = c - 68; }
  else if (c < 134) { kind = 3; g = c - 132; }
  else if (c < 136) { kind = 4; }
  else if (c < 200) { kind = 0; g = c - 136; }
  else if (c < 202) { kind = 2; g = c - 200; }
  u16 out[16];
  if (kind == 0 || kind == 1) {
    const int* q = qw + (size_t)o * 1024 + g * 16;
    const float s = sc[(size_t)o * 64 + g];
#pragma unroll
    for (int j = 0; j < 16; ++j) {
      float w = ((float)q[j] * (2.0f / 15.0f) - 1.0f) * s;
      u16 h, l; split_bf(w, h, l);
      out[j] = (kind == 0) ? h : l;
    }
  } else if (kind == 2 || kind == 3) {
    const float* B = lb + (size_t)o * RLORA + g * 16;
#pragma unroll
    for (int j = 0; j < 16; ++j) {
      u16 h, l; split_bf(B[j], h, l);
      out[j] = (kind == 2) ? h : l;
    }
  } else {
#pragma unroll
    for (int j = 0; j < 16; ++j) out[j] = 0;
  }
  u16* w = Wc + (size_t)o * KC + c * 16;
#pragma unroll
  for (int j = 0; j < 16; ++j) w[j] = out[j];
}

// Aa[li][r][0:1024]=lora_A (split); rest 0  (all 18 layers) — R5 verbatim
__global__ void pack_a_k(const float* __restrict__ la,
                         u16* __restrict__ Ah, u16* __restrict__ Al) {
  const int idx = blockIdx.x * 256 + threadIdx.x;
  if (idx >= NLIN * RLORA * (KP / 16)) return;
  const int g = idx % (KP / 16);
  const int rem = idx / (KP / 16);
  u16 h[16], l[16];
  if (g < 64) {
    const float* a = la + (size_t)rem * 1024 + g * 16;
#pragma unroll
    for (int j = 0; j < 16; ++j) split_bf(a[j], h[j], l[j]);
  } else {
#pragma unroll
    for (int j = 0; j < 16; ++j) { h[j] = 0; l[j] = 0; }
  }
  u16* ph = Ah + (size_t)rem * KP + g * 16;
  u16* pl = Al + (size_t)rem * KP + g * 16;
#pragma unroll
  for (int j = 0; j < 16; ++j) { ph[j] = h[j]; pl[j] = l[j]; }
}

// acts: split(x) into hi/lo; pads (>=1024) of BOTH buffer pairs zeroed. (R5)
__global__ void pack_x_k(const float* __restrict__ x,
                         u16* __restrict__ aAh, u16* __restrict__ aAl,
                         u16* __restrict__ aBh, u16* __restrict__ aBl) {
  const int idx = blockIdx.x * 256 + threadIdx.x;
  if (idx >= NTOK * (KP / 16)) return;
  const int g = idx % (KP / 16);
  const int n = idx / (KP / 16);
  const size_t dofs = (size_t)n * KP + g * 16;
  if (g < 64) {
    const float* xp = x + (size_t)n * DIM + g * 16;
#pragma unroll
    for (int j = 0; j < 16; ++j) {
      u16 h, l;
      split_bf(xp[j], h, l);
      aAh[dofs + j] = h; aAl[dofs + j] = l;
    }
  } else {
#pragma unroll
    for (int j = 0; j < 16; ++j) {
      aAh[dofs + j] = 0; aAl[dofs + j] = 0;
      aBh[dofs + j] = 0; aBl[dofs + j] = 0;
    }
  }
}

// ---------------------------------------------------------------------------
// t_k: t = xh @ (Ah+Al)^T -> Xh cols [1024:1056). R5 verbatim (verified).
// ---------------------------------------------------------------------------
__global__ __launch_bounds__(256, 4) void t_k(
    u16* __restrict__ Xh, const u16* __restrict__ LAh,
    const u16* __restrict__ LAl) {
  __shared__ __align__(16) u16 sX[64 * 64];
  const int tid = threadIdx.x, lane = tid & 63, wave = tid >> 6;
  const int row0 = blockIdx.x * 64;
  const int fr = lane & 15, sl = lane >> 4;
  const int xr = tid >> 3, xs = tid & 7;

  f32x4 acc[2];
  acc[0] = {0.f, 0.f, 0.f, 0.f};
  acc[1] = {0.f, 0.f, 0.f, 0.f};

  for (int t = 0; t < 16; ++t) {
    const int kofs = t * 64;
    gld16(Xh + (size_t)(row0 + xr) * KP + kofs + (xs ^ (xr & 7)) * 8,
          &sX[tid * 8]);
    gld16(Xh + (size_t)(row0 + 32 + xr) * KP + kofs + (xs ^ (xr & 7)) * 8,
          &sX[2048 + tid * 8]);
    __syncthreads();
    short8 a[2];
#pragma unroll
    for (int kk = 0; kk < 2; ++kk) {
      const int arow = wave * 16 + fr;
      a[kk] = *(const short8*)&sX[arow * 64 + (((kk * 4 + sl) ^ (fr & 7))) * 8];
    }
#pragma unroll
    for (int n = 0; n < 2; ++n) {
      const int ar = n * 16 + fr;
#pragma unroll
      for (int kk = 0; kk < 2; ++kk) {
        const int ac = kofs + kk * 32 + sl * 8;
        short8 bh = *(const short8*)&LAh[(size_t)ar * KP + ac];
        short8 bl = *(const short8*)&LAl[(size_t)ar * KP + ac];
        acc[n] = __builtin_amdgcn_mfma_f32_16x16x32_bf16(a[kk], bh, acc[n], 0, 0, 0);
        acc[n] = __builtin_amdgcn_mfma_f32_16x16x32_bf16(a[kk], bl, acc[n], 0, 0, 0);
      }
    }
    __syncthreads();
  }
  const int crow0 = row0 + wave * 16 + (lane >> 4) * 4;
#pragma unroll
  for (int n = 0; n < 2; ++n) {
    const int col = DIM + n * 16 + fr;
#pragma unroll
    for (int r = 0; r < 4; ++r)
      Xh[(size_t)(crow0 + r) * KP + col] = f2bf(acc[n][r]);
  }
}

// ---------------------------------------------------------------------------
// 8-phase 256x256 GEMM over KC (NSTEP=51 K-tiles of 64).
// Waves: 8 = 2M x 4N; per-wave out 128x64; acc[8][4].
// Stage schedule per K-tile t: P0:A0(t+1) P1:A1(t+1) P2:B0(t+2) P3:B1(t+2);
// vmcnt(4) before tile-boundary barrier (leaves B(t+2)'s 4 loads in flight).
// ---------------------------------------------------------------------------
#define MFMA16(Q, A0, A1)                                                   \
  _Pragma("unroll")                                                         \
  for (int kk = 0; kk < 2; ++kk) {                                          \
    _Pragma("unroll")                                                       \
    for (int ni = 0; ni < 4; ++ni) {                                        \
      acc[2 * (Q)][ni] = __builtin_amdgcn_mfma_f32_16x16x32_bf16(           \
          A0[kk], b[ni][kk], acc[2 * (Q)][ni], 0, 0, 0);                    \
      acc[2 * (Q) + 1][ni] = __builtin_amdgcn_mfma_f32_16x16x32_bf16(       \
          A1[kk], b[ni][kk], acc[2 * (Q) + 1][ni], 0, 0, 0);                \
    }                                                                       \
  }

#define RD_A(Q, A0, A1)                                                     \
  {                                                                         \
    const int hb = (c * 2 + wr) * 8192;                                     \
    const int l0 = (2 * (Q)) * 16 + fr, l1 = (2 * (Q) + 1) * 16 + fr;       \
    _Pragma("unroll")                                                       \
    for (int kk = 0; kk < 2; ++kk) {                                        \
      const int sw = (((kk * 4 + sl) ^ (fr & 7))) * 8;                      \
      A0[kk] = *(const short8*)&sA[hb + l0 * 64 + sw];                      \
      A1[kk] = *(const short8*)&sA[hb + l1 * 64 + sw];                      \
    }                                                                       \
  }

template <int MODE>
__global__ __launch_bounds__(512, 2) void gemm8_k(
    const u16* __restrict__ Xh, const u16* __restrict__ Xl,
    const u16* __restrict__ Wc, const float* __restrict__ bias,
    const float* __restrict__ resid, float* __restrict__ outf,
    u16* __restrict__ Oh, u16* __restrict__ Ol) {
  __shared__ __align__(16) u16 sA[2 * 2 * 8192];   // [buf][half][128*64]
  __shared__ __align__(16) u16 sB[2 * 2 * 8192];
  const int tid = threadIdx.x;
  const int lane = tid & 63, wave = tid >> 6;
  const int wr = wave >> 2, wc = wave & 3;

  // XCD row-panel grouping (R5-proven): xcd k owns row-panels [k*8,(k+1)*8)
  const int flat = blockIdx.x;
  const int xcd = flat & 7, idx = flat >> 3;
  const int row0 = (xcd * 8 + (idx >> 2)) * 256;
  const int col0 = (idx & 3) * 256;

  const int rt = tid >> 3;                 // staging row 0..63
  const int st = tid & 7;                  // staging slot
  const int swz = (st ^ (rt & 7)) * 8;     // pre-swizzled source col offset
  const int fr = lane & 15, sl = lane >> 4;

  f32x4 acc[8][4];
#pragma unroll
  for (int i = 0; i < 8; ++i)
#pragma unroll
    for (int j = 0; j < 4; ++j) acc[i][j] = {0.f, 0.f, 0.f, 0.f};

  auto stA = [&](int buf, int s, int half) {
    const u16* src = (s < 34) ? Xh : Xl;
    const int cb = (s < 17 ? s : (s < 34 ? s - 17 : s - 34)) * 64;
#pragma unroll
    for (int i = 0; i < 2; ++i)
      gld16(src + (size_t)(row0 + half * 128 + i * 64 + rt) * KP + cb + swz,
            &sA[(buf * 2 + half) * 8192 + i * 4096 + tid * 8]);
  };
  auto stB = [&](int buf, int s, int half) {
#pragma unroll
    for (int i = 0; i < 2; ++i)
      gld16(Wc + (size_t)(col0 + half * 128 + i * 64 + rt) * KC + s * 64 + swz,
            &sB[(buf * 2 + half) * 8192 + i * 4096 + tid * 8]);
  };

  // prologue: tile0 fully (8 gld) + tile1 B halves (4 gld)
  stA(0, 0, 0); stA(0, 0, 1);
  stB(0, 0, 0); stB(0, 0, 1);
  stB(1, 1, 0); stB(1, 1, 1);
  asm volatile("s_waitcnt vmcnt(4)" ::: "memory");   // tile0 landed
  __builtin_amdgcn_s_barrier();
  __builtin_amdgcn_sched_barrier(0);

  for (int t = 0; t < NSTEP; ++t) {
    const int c = t & 1;
    short8 b[4][2];
    // -------- phase 0: B-frags (8 reads) + A m=0,1; stage A0(t+1) --------
    {
#pragma unroll
      for (int ni = 0; ni < 4; ++ni) {
        const int br = wc * 64 + ni * 16 + fr;
        const int base = (c * 2 + (br >> 7)) * 8192 + (br & 127) * 64;
#pragma unroll
        for (int kk = 0; kk < 2; ++kk)
          b[ni][kk] =
              *(const short8*)&sB[base + (((kk * 4 + sl) ^ (fr & 7))) * 8];
      }
      short8 a0[2], a1[2];
      RD_A(0, a0, a1)
      if (t + 1 < NSTEP) stA(c ^ 1, t + 1, 0);
      __builtin_amdgcn_s_barrier();
      asm volatile("s_waitcnt lgkmcnt(0)" ::: "memory");
      __builtin_amdgcn_sched_barrier(0);
      __builtin_amdgcn_s_setprio(1);
      MFMA16(0, a0, a1)
      __builtin_amdgcn_s_setprio(0);
      __builtin_amdgcn_s_barrier();
    }
    // -------- phase 1: A m=2,3; stage A1(t+1) --------
    {
      short8 a0[2], a1[2];
      RD_A(1, a0, a1)
      if (t + 1 < NSTEP) stA(c ^ 1, t + 1, 1);
      __builtin_amdgcn_s_barrier();
      asm volatile("s_waitcnt lgkmcnt(0)" ::: "memory");
      __builtin_amdgcn_sched_barrier(0);
      __builtin_amdgcn_s_setprio(1);
      MFMA16(1, a0, a1)
      __builtin_amdgcn_s_setprio(0);
      __builtin_amdgcn_s_barrier();
    }
    // -------- phase 2: A m=4,5; stage B0(t+2) --------
    {
      short8 a0[2], a1[2];
      RD_A(2, a0, a1)
      if (t + 2 < NSTEP) stB(c, t + 2, 0);
      __builtin_amdgcn_s_barrier();
      asm volatile("s_waitcnt lgkmcnt(0)" ::: "memory");
      __builtin_amdgcn_sched_barrier(0);
      __builtin_amdgcn_s_setprio(1);
      MFMA16(2, a0, a1)
      __builtin_amdgcn_s_setprio(0);
      __builtin_amdgcn_s_barrier();
    }
    // -------- phase 3: A m=6,7; stage B1(t+2); counted vmcnt; barrier ----
    {
      short8 a0[2], a1[2];
      RD_A(3, a0, a1)
      if (t + 2 < NSTEP) stB(c, t + 2, 1);
      __builtin_amdgcn_s_barrier();
      asm volatile("s_waitcnt lgkmcnt(0)" ::: "memory");
      __builtin_amdgcn_sched_barrier(0);
      __builtin_amdgcn_s_setprio(1);
      MFMA16(3, a0, a1)
      __builtin_amdgcn_s_setprio(0);
      // all of tile t+1 (A staged P0/P1, B staged last tile) must land;
      // leave only B(t+2)'s 4 loads in flight.
      if (t + 2 < NSTEP)
        asm volatile("s_waitcnt vmcnt(4)" ::: "memory");
      else
        asm volatile("s_waitcnt vmcnt(0)" ::: "memory");
      __builtin_amdgcn_s_barrier();
      __builtin_amdgcn_sched_barrier(0);
    }
  }

  // epilogue (C/D: col = lane&15, row = (lane>>4)*4 + reg)
  const int crow0 = row0 + wr * 128 + (lane >> 4) * 4;
  const int ccolb = col0 + wc * 64 + fr;
#pragma unroll
  for (int ni = 0; ni < 4; ++ni) {
    const int col = ccolb + ni * 16;
    const float bvv = bias[col];
#pragma unroll
    for (int mi = 0; mi < 8; ++mi) {
#pragma unroll
      for (int r = 0; r < 4; ++r) {
        const int rw = crow0 + mi * 16 + r;
        float v = acc[mi][ni][r] + bvv;
        if (MODE == 0) {
          v = fmaxf(v, 0.f);
          u16 h, l; split_bf(v, h, l);
          Oh[(size_t)rw * KP + col] = h;
          Ol[(size_t)rw * KP + col] = l;
        } else {
          v += resid[(size_t)rw * DIM + col];
          outf[(size_t)rw * DIM + col] = v;
        }
      }
    }
  }
}

// ---------------------------------------------------------------------------
// LayerNorm -> fp32 resid + split act out (R5 verbatim)
// ---------------------------------------------------------------------------
__global__ __launch_bounds__(256) void ln_k(
    const float* __restrict__ y, const float* __restrict__ g,
    const float* __restrict__ b, float* __restrict__ ro,
    u16* __restrict__ Oh, u16* __restrict__ Ol) {
  const int row = blockIdx.x, tid = threadIdx.x;
  const int lane = tid & 63, wave = tid >> 6;
  __shared__ float r1[4], r2[4];
  const float4 v = ((const float4*)(y + (size_t)row * DIM))[tid];
  float s = v.x + v.y + v.z + v.w;
#pragma unroll
  for (int o = 32; o > 0; o >>= 1) s += __shfl_down(s, o);
  if (lane == 0) r1[wave] = s;
  __syncthreads();
  const float mean = (r1[0] + r1[1] + r1[2] + r1[3]) * (1.0f / DIM);
  const float d0 = v.x - mean, d1 = v.y - mean, d2 = v.z - mean, d3 = v.w - mean;
  float q = d0 * d0 + d1 * d1 + d2 * d2 + d3 * d3;
#pragma unroll
  for (int o = 32; o > 0; o >>= 1) q += __shfl_down(q, o);
  if (lane == 0) r2[wave] = q;
  __syncthreads();
  const float var = (r2[0] + r2[1] + r2[2] + r2[3]) * (1.0f / DIM);
  const float rs = rsqrtf(var + 1e-5f);
  const float4 gv = ((const float4*)g)[tid];
  const float4 bv = ((const float4*)b)[tid];
  const float o0 = d0 * rs * gv.x + bv.x;
  const float o1 = d1 * rs * gv.y + bv.y;
  const float o2 = d2 * rs * gv.z + bv.z;
  const float o3 = d3 * rs * gv.w + bv.w;
  ((float4*)(ro + (size_t)row * DIM))[tid] = make_float4(o0, o1, o2, o3);
  u16 h0, l0, h1, l1, h2, l2, h3, l3;
  split_bf(o0, h0, l0); split_bf(o1, h1, l1);
  split_bf(o2, h2, l2); split_bf(o3, h3, l3);
  ushort4 hh; hh.x = h0; hh.y = h1; hh.z = h2; hh.w = h3;
  ushort4 ll; ll.x = l0; ll.y = l1; ll.z = l2; ll.w = l3;
  *(ushort4*)&Oh[(size_t)row * KP + tid * 4] = hh;
  *(ushort4*)&Ol[(size_t)row * KP + tid * 4] = ll;
}

// ---------------------------------------------------------------------------
extern "C" void kernel_launch(void* const* d_in, const int* in_sizes, int n_in,
                              void* d_out, int out_size, void* d_ws, size_t ws_size,
                              hipStream_t stream) {
  const float* x      = (const float*)d_in[0];
  const int*   qw     = (const int*)d_in[1];
  const float* scales = (const float*)d_in[2];
  const float* bias   = (const float*)d_in[3];
  const float* lora_A = (const float*)d_in[4];
  const float* lora_B = (const float*)d_in[5];
  const float* ln_g   = (const float*)d_in[6];
  const float* ln_b   = (const float*)d_in[7];

  char* p = (char*)d_ws;
  auto carve = [&](size_t bytes) {
    char* r = p;
    p += (bytes + 255) & ~(size_t)255;
    return (void*)r;
  };
  // ws ~ 222 MB: Wc 6.7 + A 5 + acts 142.6 + residb 67.1
  u16* Wc  = (u16*)carve((size_t)1024 * KC * 2);       // one-layer ring
  u16* Ah  = (u16*)carve((size_t)NLIN * RLORA * KP * 2);
  u16* Al  = (u16*)carve((size_t)NLIN * RLORA * KP * 2);
  u16* aAh = (u16*)carve((size_t)NTOK * KP * 2);
  u16* aAl = (u16*)carve((size_t)NTOK * KP * 2);
  u16* aBh = (u16*)carve((size_t)NTOK * KP * 2);
  u16* aBl = (u16*)carve((size_t)NTOK * KP * 2);
  float* residb = (float*)carve((size_t)NTOK * DIM * 4);
  float* ybuf   = (float*)d_out;                       // pre-LN sum in d_out

  {
    const int tot = NLIN * RLORA * (KP / 16);
    pack_a_k<<<(tot + 255) / 256, 256, 0, stream>>>(lora_A, Ah, Al);
  }
  {
    const int tot = NTOK * (KP / 16);
    pack_x_k<<<(tot + 255) / 256, 256, 0, stream>>>(x, aAh, aAl, aBh, aBl);
  }

  u16 *inH = aAh, *inL = aAl, *outH = aBh, *outL = aBl;
  const float* resid = x;
  const int wtot = 1024 * (KC / 16);
  for (int blk = 0; blk < NBLK; ++blk) {
    for (int j = 0; j < 3; ++j) {
      const int li = 3 * blk + j;
      pack_w_k<<<(wtot + 255) / 256, 256, 0, stream>>>(
          qw + (size_t)li * DIM * DIM, scales + (size_t)li * DIM * (DIM / 16),
          lora_B + (size_t)li * DIM * RLORA, Wc);
      t_k<<<NTOK / 64, 256, 0, stream>>>(
          inH, Ah + (size_t)li * RLORA * KP, Al + (size_t)li * RLORA * KP);
      const float* lb = bias + (size_t)li * DIM;
      if (j < 2) {
        gemm8_k<0><<<dim3(256), 512, 0, stream>>>(inH, inL, Wc, lb,
                                                  nullptr, nullptr, outH, outL);
        u16* t;
        t = inH; inH = outH; outH = t;
        t = inL; inL = outL; outL = t;
      } else {
        gemm8_k<1><<<dim3(256), 512, 0, stream>>>(inH, inL, Wc, lb,
                                                  resid, ybuf, nullptr, nullptr);
        if (blk < NBLK - 1) {
          ln_k<<<NTOK, 256, 0, stream>>>(ybuf, ln_g + (size_t)blk * DIM,
                                         ln_b + (size_t)blk * DIM, residb,
                                         outH, outL);
          resid = residb;
          u16* t;
          t = inH; inH = outH; outH = t;
          t = inL; inL = outL; outL = t;
        }
      }
    }
  }
  (void)in_sizes; (void)n_in; (void)out_size; (void)ws_size;
}